// Round 7
// baseline (269.461 us; speedup 1.0000x reference)
//
#include <hip/hip_runtime.h>
#include <stdint.h>
#include <stddef.h>

// Problem constants
#define B_N   4096
#define NSENT 64
#define DDIM  768
#define TOPK  5
#define FAN1  4608   // (TOPK+1)*768
#define H1DIM 1024
#define NCLS  4
#define KDIM  4608
#define KSPLIT 4
#define KQ    1152   // K per block = KDIM/KSPLIT

typedef __attribute__((ext_vector_type(8))) __bf16 bf16x8;
typedef __attribute__((ext_vector_type(4))) float  f32x4;

__device__ __forceinline__ unsigned short f2bf(float f) {
    unsigned int u = __float_as_uint(f);
    unsigned int r = (u + 0x7fffu + ((u >> 16) & 1u)) >> 16;
    return (unsigned short)r;
}

__device__ __forceinline__ void gl_lds16(const void* g, void* l) {
    __builtin_amdgcn_global_load_lds((__attribute__((address_space(1))) void*)(g),
                                     (__attribute__((address_space(3))) void*)(l),
                                     16, 0, 0);
}

// ---------------------------------------------------------------------------
// Kernel A: per batch row b: sims[n] = <sim_stance[b], sim_body[b,n]> (f32),
// top-5 (strict >, tie -> lower index, matching jax.lax.top_k), then gather
// nli_stance + 5 nli_body rows -> xx[b] as bf16 (4608 elems).
// ---------------------------------------------------------------------------
__global__ __launch_bounds__(256) void k_topk_gather(
    const float* __restrict__ sim_stance,
    const float* __restrict__ sim_body,
    const float* __restrict__ nli_stance,
    const float* __restrict__ nli_body,
    unsigned short* __restrict__ xx)
{
    const int b    = blockIdx.x;
    const int tid  = threadIdx.x;
    const int lane = tid & 63;
    const int wave = tid >> 6;
    const int g    = lane >> 4;     // row-group 0..3
    const int c    = lane & 15;     // column slice
    __shared__ float sims[NSENT];
    __shared__ int   topidx[TOPK];

    // stance slice: float4 indices c + 16*j, j = 0..11 (48 floats/lane)
    const float4* st4 = (const float4*)(sim_stance + (size_t)b * DDIM);
    float4 st[12];
    #pragma unroll
    for (int j = 0; j < 12; ++j) st[j] = st4[c + 16 * j];

    const float* bodyb = sim_body + (size_t)b * NSENT * DDIM;
    #pragma unroll 1
    for (int it = 0; it < 4; ++it) {
        const int r = wave * 16 + it * 4 + g;
        const float4* r4 = (const float4*)(bodyb + (size_t)r * DDIM);
        float p = 0.f;
        #pragma unroll
        for (int j = 0; j < 12; ++j) {
            float4 v = r4[c + 16 * j];
            p += v.x*st[j].x + v.y*st[j].y + v.z*st[j].z + v.w*st[j].w;
        }
        #pragma unroll
        for (int off = 8; off; off >>= 1) p += __shfl_xor(p, off);
        if (c == 0) sims[r] = p;
    }
    __syncthreads();

    // wave 0: 5x butterfly argmax (strict >, tie -> lower index)
    if (wave == 0) {
        float v = sims[lane];
        #pragma unroll
        for (int k = 0; k < TOPK; ++k) {
            float bv = v; int bi = lane;
            #pragma unroll
            for (int off = 32; off; off >>= 1) {
                float ov = __shfl_xor(bv, off);
                int   oi = __shfl_xor(bi, off);
                if (ov > bv || (ov == bv && oi < bi)) { bv = ov; bi = oi; }
            }
            if (lane == 0) topidx[k] = bi;
            if (lane == bi) v = -3.402823466e38f;
        }
    }
    __syncthreads();

    // gather + f32->bf16 convert: 6 segments of 768 floats (192 float4 each)
    unsigned short* xrow = xx + (size_t)b * FAN1;
    for (int task = tid; task < 1152; task += 256) {
        const int seg = task / 192;
        const int t   = task - seg * 192;
        const float* src = (seg == 0)
            ? (nli_stance + (size_t)b * DDIM)
            : (nli_body + ((size_t)b * NSENT + topidx[seg - 1]) * DDIM);
        float4 v = ((const float4*)src)[t];
        ushort4 o;
        o.x = f2bf(v.x); o.y = f2bf(v.y); o.z = f2bf(v.z); o.w = f2bf(v.w);
        ((ushort4*)(xrow + seg * DDIM))[t] = o;
    }
}

// ---------------------------------------------------------------------------
// W1 f32 -> bf16 (row-major [H1][FAN1] preserved; acts as B^T for the GEMM)
// ---------------------------------------------------------------------------
__global__ __launch_bounds__(256) void k_f32_to_bf16x4(
    const float* __restrict__ in, unsigned short* __restrict__ o, int n4)
{
    int i = blockIdx.x * 256 + threadIdx.x;
    if (i < n4) {
        float4 v = ((const float4*)in)[i];
        ushort4 r;
        r.x = f2bf(v.x); r.y = f2bf(v.y); r.z = f2bf(v.z); r.w = f2bf(v.w);
        ((ushort4*)o)[i] = r;
    }
}

// ---------------------------------------------------------------------------
// GEMM1 (split-K=4): P[ks][m][h] = sum_{k in quarter ks} xx[m][k]*W1[h][k]
// M=4096 N=1024 K=4608, bf16 MFMA 16x16x32.
// m97 geometry: BM=BN=128, BK=64, 4 waves (2x2), wave tile 64x64, 4x4
// fragments -> 32 MFMA / 8 gl_lds per wave per K-step. Split-K=4 -> grid
// 1024 = up to 4 blocks/CU co-resident; __launch_bounds__(256,3) caps VGPR
// so >=3 blocks/CU fit (m132: 3->2 blocks/CU was 874->508 TF — occupancy
// is what hides the per-K-step vmcnt(0)+barrier drain). Bias/ReLU deferred.
// XCD swizzle: wk = (bid&7)*128 + (bid>>3); each XCD gets one ks quarter x
// 16 bm x all 8 bn (A/B panel ~7 MB, streaming L2 reuse). nwg%8==0 ✓.
// LDS chunk swizzle (both-sides involution): slot s of row r holds global
// chunk s ^ (r&7); gl_lds dest linear, per-lane GLOBAL source permuted;
// fragment reads apply the same XOR -> balanced banks.
// ---------------------------------------------------------------------------
__global__ __launch_bounds__(256, 3) void k_gemm1(
    const unsigned short* __restrict__ A,   // xx bf16 [4096][4608]
    const unsigned short* __restrict__ W,   // W1 bf16 [1024][4608]
    float* __restrict__ P)                  // [4][4096][1024] f32 partials
{
    constexpr int BM = 128, BN = 128, BK = 64;
    constexpr int K = KDIM;
    __shared__ unsigned short lA[BM * BK];  // 16 KB
    __shared__ unsigned short lB[BN * BK];  // 16 KB

    const int tid = threadIdx.x, lane = tid & 63, wave = tid >> 6;
    const int bid = blockIdx.x;
    const int wk  = (bid & 7) * 128 + (bid >> 3);  // XCD-grouped work id
    const int ks  = wk >> 8;                       // K-quarter 0..3
    const int rem = wk & 255;
    const int bm  = rem >> 3, bn = rem & 7;
    const int wm = wave >> 1, wn = wave & 1;
    const int k0 = ks * KQ;

    // ---- staging setup: 1024 chunks per side, 4 per thread (j=0..3) ----
    const int rowq = wave * 8 + (lane >> 3);
    const int sc   = (lane & 7) ^ (lane >> 3);  // swizzled global chunk
    const unsigned short* gA[4];
    const unsigned short* gB[4];
    #pragma unroll
    for (int j = 0; j < 4; ++j) {
        gA[j] = A + (size_t)(bm * BM + j * 32 + rowq) * K + k0 + sc * 8;
        gB[j] = W + (size_t)(bn * BN + j * 32 + rowq) * K + k0 + sc * 8;
    }
    unsigned short* lAd[4];
    unsigned short* lBd[4];
    #pragma unroll
    for (int j = 0; j < 4; ++j) {
        lAd[j] = &lA[(j * 256 + wave * 64) * 8];
        lBd[j] = &lB[(j * 256 + wave * 64) * 8];
    }

    // ---- fragment read setup (swizzled) ----
    const int r16 = lane & 15;
    const int p0  = (lane >> 4) ^ (r16 & 7);   // slot for k-half 0 of BK
    const int p1  = p0 ^ 4;                    // slot for k-half 1 of BK
    const unsigned short* paBase = &lA[(wm * 64 + r16) * BK];
    const unsigned short* pbBase = &lB[(wn * 64 + r16) * BK];

    f32x4 acc[4][4];
    #pragma unroll
    for (int m = 0; m < 4; ++m)
        #pragma unroll
        for (int n = 0; n < 4; ++n) acc[m][n] = {0.f, 0.f, 0.f, 0.f};

    for (int kt = 0; kt < KQ / BK; ++kt) {
        #pragma unroll
        for (int j = 0; j < 4; ++j) { gl_lds16(gA[j], lAd[j]); gA[j] += BK; }
        #pragma unroll
        for (int j = 0; j < 4; ++j) { gl_lds16(gB[j], lBd[j]); gB[j] += BK; }
        __syncthreads();   // vmcnt(0) drain; hidden by co-resident blocks

        bf16x8 fa[4][2], fb[4][2];
        #pragma unroll
        for (int m = 0; m < 4; ++m) {
            fa[m][0] = *(const bf16x8*)(paBase + m * 16 * BK + p0 * 8);
            fa[m][1] = *(const bf16x8*)(paBase + m * 16 * BK + p1 * 8);
        }
        #pragma unroll
        for (int n = 0; n < 4; ++n) {
            fb[n][0] = *(const bf16x8*)(pbBase + n * 16 * BK + p0 * 8);
            fb[n][1] = *(const bf16x8*)(pbBase + n * 16 * BK + p1 * 8);
        }
        #pragma unroll
        for (int h = 0; h < 2; ++h)
            #pragma unroll
            for (int m = 0; m < 4; ++m)
                #pragma unroll
                for (int n = 0; n < 4; ++n)
                    acc[m][n] = __builtin_amdgcn_mfma_f32_16x16x32_bf16(
                        fa[m][h], fb[n][h], acc[m][n], 0, 0, 0);
        __syncthreads();
    }

    // epilogue: C/D layout col=lane&15, row=(lane>>4)*4+reg; raw partials
    float* Pk = P + (size_t)ks * B_N * H1DIM;
    const int colbase = bn * BN + wn * 64 + r16;
    const int rowbase = bm * BM + wm * 64 + (lane >> 4) * 4;
    #pragma unroll
    for (int n = 0; n < 4; ++n) {
        const int col = colbase + n * 16;
        #pragma unroll
        for (int m = 0; m < 4; ++m) {
            const int row = rowbase + m * 16;
            #pragma unroll
            for (int j = 0; j < 4; ++j)
                Pk[(size_t)(row + j) * H1DIM + col] = acc[m][n][j];
        }
    }
}

// ---------------------------------------------------------------------------
// GEMM2 (+ fused split-K reduce, bias, relu):
// h[b][:] = relu(P0[b]+P1[b]+P2[b]+P3[b]+b1); out[b][c] = <h, W2[c]> + b2[c].
// One wave per batch row; W2 (16 KB) + b1 (4 KB) staged in LDS.
// ---------------------------------------------------------------------------
__global__ __launch_bounds__(256) void k_gemm2(
    const float* __restrict__ P, const float* __restrict__ W2,
    const float* __restrict__ b1, const float* __restrict__ b2,
    float* __restrict__ out)
{
    __shared__ float w2s[NCLS * H1DIM + H1DIM];
    const int tid = threadIdx.x, lane = tid & 63, wave = tid >> 6;
    const int row = blockIdx.x * 4 + wave;
    for (int i = tid; i < NCLS * H1DIM; i += 256) w2s[i] = W2[i];
    for (int i = tid; i < H1DIM; i += 256) w2s[NCLS * H1DIM + i] = b1[i];
    __syncthreads();

    const float4* p0 = (const float4*)(P + (size_t)row * H1DIM);
    const float4* p1 = (const float4*)(P + (size_t)(B_N + row) * H1DIM);
    const float4* p2 = (const float4*)(P + (size_t)(2 * B_N + row) * H1DIM);
    const float4* p3 = (const float4*)(P + (size_t)(3 * B_N + row) * H1DIM);
    const float4* w0 = (const float4*)&w2s[0];
    const float4* w1 = (const float4*)&w2s[H1DIM];
    const float4* w2 = (const float4*)&w2s[2 * H1DIM];
    const float4* w3 = (const float4*)&w2s[3 * H1DIM];
    const float4* bb = (const float4*)&w2s[4 * H1DIM];
    float a0 = 0.f, a1 = 0.f, a2 = 0.f, a3 = 0.f;
    #pragma unroll
    for (int j = 0; j < 4; ++j) {
        const int idx = j * 64 + lane;
        float4 x0 = p0[idx], x1 = p1[idx], x2 = p2[idx], x3 = p3[idx];
        float4 bv = bb[idx];
        float4 h;
        h.x = ((x0.x + x1.x) + x2.x) + x3.x + bv.x; h.x = h.x > 0.f ? h.x : 0.f;
        h.y = ((x0.y + x1.y) + x2.y) + x3.y + bv.y; h.y = h.y > 0.f ? h.y : 0.f;
        h.z = ((x0.z + x1.z) + x2.z) + x3.z + bv.z; h.z = h.z > 0.f ? h.z : 0.f;
        h.w = ((x0.w + x1.w) + x2.w) + x3.w + bv.w; h.w = h.w > 0.f ? h.w : 0.f;
        float4 xv;
        xv = w0[idx]; a0 += h.x*xv.x + h.y*xv.y + h.z*xv.z + h.w*xv.w;
        xv = w1[idx]; a1 += h.x*xv.x + h.y*xv.y + h.z*xv.z + h.w*xv.w;
        xv = w2[idx]; a2 += h.x*xv.x + h.y*xv.y + h.z*xv.z + h.w*xv.w;
        xv = w3[idx]; a3 += h.x*xv.x + h.y*xv.y + h.z*xv.z + h.w*xv.w;
    }
    #pragma unroll
    for (int off = 32; off; off >>= 1) {
        a0 += __shfl_xor(a0, off);
        a1 += __shfl_xor(a1, off);
        a2 += __shfl_xor(a2, off);
        a3 += __shfl_xor(a3, off);
    }
    if (lane == 0) {
        float* o = out + (size_t)row * NCLS;
        o[0] = a0 + b2[0]; o[1] = a1 + b2[1]; o[2] = a2 + b2[2]; o[3] = a3 + b2[3];
    }
}

// ---------------------------------------------------------------------------
// Workspace layout (bytes; ws_size ~3.2 GB per poison-fill counters):
//   [0, 37748736)                  xx bf16          4096*4608*2
//   [37748736, 47185920)           W1 bf16          1024*4608*2
//   [47185920, 114294784)          P f32 partials   4*4096*1024*4
// ---------------------------------------------------------------------------
extern "C" void kernel_launch(void* const* d_in, const int* in_sizes, int n_in,
                              void* d_out, int out_size, void* d_ws, size_t ws_size,
                              hipStream_t stream)
{
    const float* sim_stance = (const float*)d_in[0];
    const float* nli_stance = (const float*)d_in[1];
    const float* sim_body   = (const float*)d_in[2];
    const float* nli_body   = (const float*)d_in[3];
    const float* W1 = (const float*)d_in[4];
    const float* b1 = (const float*)d_in[5];
    const float* W2 = (const float*)d_in[6];
    const float* b2 = (const float*)d_in[7];
    float* out = (float*)d_out;

    char* ws = (char*)d_ws;
    unsigned short* xx  = (unsigned short*)ws;
    unsigned short* w1b = (unsigned short*)(ws + 37748736u);
    float*          P   = (float*)(ws + 37748736u + 9437184u);

    k_f32_to_bf16x4<<<dim3(4608), dim3(256), 0, stream>>>(W1, w1b, 1179648);
    k_topk_gather<<<dim3(B_N), dim3(256), 0, stream>>>(sim_stance, sim_body,
                                                       nli_stance, nli_body, xx);
    k_gemm1<<<dim3(1024), dim3(256), 0, stream>>>(xx, w1b, P);
    k_gemm2<<<dim3(1024), dim3(256), 0, stream>>>(P, W2, b1, b2, out);
}

// Round 8
// 257.318 us; speedup vs baseline: 1.0472x; 1.0472x over previous
//
#include <hip/hip_runtime.h>
#include <stdint.h>
#include <stddef.h>

// Problem constants
#define B_N   4096
#define NSENT 64
#define DDIM  768
#define TOPK  5
#define FAN1  4608   // (TOPK+1)*768
#define H1DIM 1024
#define NCLS  4
#define KDIM  4608
#define KHALF 2304   // split-K=2: K per block

typedef __attribute__((ext_vector_type(8))) __bf16 bf16x8;
typedef __attribute__((ext_vector_type(4))) float  f32x4;

__device__ __forceinline__ unsigned short f2bf(float f) {
    unsigned int u = __float_as_uint(f);
    unsigned int r = (u + 0x7fffu + ((u >> 16) & 1u)) >> 16;
    return (unsigned short)r;
}

__device__ __forceinline__ void gl_lds16(const void* g, void* l) {
    __builtin_amdgcn_global_load_lds((__attribute__((address_space(1))) void*)(g),
                                     (__attribute__((address_space(3))) void*)(l),
                                     16, 0, 0);
}

// ---------------------------------------------------------------------------
// Kernel A: per batch row b: sims[n] = <sim_stance[b], sim_body[b,n]> (f32),
// top-5 (strict >, tie -> lower index, matching jax.lax.top_k), then gather
// nli_stance + 5 nli_body rows -> xx[b] as bf16 (4608 elems).
// ---------------------------------------------------------------------------
__global__ __launch_bounds__(256) void k_topk_gather(
    const float* __restrict__ sim_stance,
    const float* __restrict__ sim_body,
    const float* __restrict__ nli_stance,
    const float* __restrict__ nli_body,
    unsigned short* __restrict__ xx)
{
    const int b    = blockIdx.x;
    const int tid  = threadIdx.x;
    const int lane = tid & 63;
    const int wave = tid >> 6;
    const int g    = lane >> 4;     // row-group 0..3
    const int c    = lane & 15;     // column slice
    __shared__ float sims[NSENT];
    __shared__ int   topidx[TOPK];

    // stance slice: float4 indices c + 16*j, j = 0..11 (48 floats/lane)
    const float4* st4 = (const float4*)(sim_stance + (size_t)b * DDIM);
    float4 st[12];
    #pragma unroll
    for (int j = 0; j < 12; ++j) st[j] = st4[c + 16 * j];

    const float* bodyb = sim_body + (size_t)b * NSENT * DDIM;
    #pragma unroll 1
    for (int it = 0; it < 4; ++it) {
        const int r = wave * 16 + it * 4 + g;
        const float4* r4 = (const float4*)(bodyb + (size_t)r * DDIM);
        float p = 0.f;
        #pragma unroll
        for (int j = 0; j < 12; ++j) {
            float4 v = r4[c + 16 * j];
            p += v.x*st[j].x + v.y*st[j].y + v.z*st[j].z + v.w*st[j].w;
        }
        #pragma unroll
        for (int off = 8; off; off >>= 1) p += __shfl_xor(p, off);
        if (c == 0) sims[r] = p;
    }
    __syncthreads();

    // wave 0: 5x butterfly argmax (strict >, tie -> lower index)
    if (wave == 0) {
        float v = sims[lane];
        #pragma unroll
        for (int k = 0; k < TOPK; ++k) {
            float bv = v; int bi = lane;
            #pragma unroll
            for (int off = 32; off; off >>= 1) {
                float ov = __shfl_xor(bv, off);
                int   oi = __shfl_xor(bi, off);
                if (ov > bv || (ov == bv && oi < bi)) { bv = ov; bi = oi; }
            }
            if (lane == 0) topidx[k] = bi;
            if (lane == bi) v = -3.402823466e38f;
        }
    }
    __syncthreads();

    // gather + f32->bf16 convert: 6 segments of 768 floats (192 float4 each)
    unsigned short* xrow = xx + (size_t)b * FAN1;
    for (int task = tid; task < 1152; task += 256) {
        const int seg = task / 192;
        const int t   = task - seg * 192;
        const float* src = (seg == 0)
            ? (nli_stance + (size_t)b * DDIM)
            : (nli_body + ((size_t)b * NSENT + topidx[seg - 1]) * DDIM);
        float4 v = ((const float4*)src)[t];
        ushort4 o;
        o.x = f2bf(v.x); o.y = f2bf(v.y); o.z = f2bf(v.z); o.w = f2bf(v.w);
        ((ushort4*)(xrow + seg * DDIM))[t] = o;
    }
}

// ---------------------------------------------------------------------------
// W1 f32 -> bf16 (row-major [H1][FAN1] preserved; acts as B^T for the GEMM)
// ---------------------------------------------------------------------------
__global__ __launch_bounds__(256) void k_f32_to_bf16x4(
    const float* __restrict__ in, unsigned short* __restrict__ o, int n4)
{
    int i = blockIdx.x * 256 + threadIdx.x;
    if (i < n4) {
        float4 v = ((const float4*)in)[i];
        ushort4 r;
        r.x = f2bf(v.x); r.y = f2bf(v.y); r.z = f2bf(v.z); r.w = f2bf(v.w);
        ((ushort4*)o)[i] = r;
    }
}

// ---------------------------------------------------------------------------
// GEMM1 (split-K=2): P[ks][m][h] = sum_{k in half ks} xx[m][k]*W1[h][k]
// M=4096 N=1024 K=4608, bf16 MFMA 16x16x32.
// Geometry as R6 (best measured): BM=BN=128, BK=64, 4 waves (2x2), wave
// tile 64x64, 32 MFMA / 8 gl_lds per wave per K-step, grid 512.
// NEW: T3-minimal prefetch pipeline with RAW barriers. Double-buffered LDS;
// STAGE(t+1) issued BEFORE computing tile t; the ONLY sync per K-step is
//   s_waitcnt vmcnt(0); s_barrier       (inline asm, after compute)
// so the next tile's global-load latency is hidden under 32 MFMA + 16
// ds_read. No __syncthreads in the loop -> no compiler vmcnt(0) drain
// between stage-issue and compute (the R4 mistake).
// Race argument: a wave's ds_reads retire before its MFMAs (lgkmcnt deps)
// which retire before it reaches s_barrier => after the barrier no wave
// still reads the buffer staged next step. vmcnt(0) before s_barrier =>
// after the barrier every wave's staged loads are visible in LDS.
// XCD swizzle: wk = (bid&7)*64 + (bid>>3). LDS chunk swizzle (both-sides
// involution): slot s of row r holds global chunk s ^ (r&7).
// ---------------------------------------------------------------------------
__global__ __launch_bounds__(256, 2) void k_gemm1(
    const unsigned short* __restrict__ A,   // xx bf16 [4096][4608]
    const unsigned short* __restrict__ W,   // W1 bf16 [1024][4608]
    float* __restrict__ P)                  // [2][4096][1024] f32 partials
{
    constexpr int BM = 128, BN = 128, BK = 64;
    constexpr int K = KDIM;
    constexpr int NT = KHALF / BK;          // 36 K-tiles
    __shared__ unsigned short lA[2][BM * BK];  // 2 x 16 KB
    __shared__ unsigned short lB[2][BN * BK];  // 2 x 16 KB

    const int tid = threadIdx.x, lane = tid & 63, wave = tid >> 6;
    const int bid = blockIdx.x;
    const int wk  = (bid & 7) * 64 + (bid >> 3);   // XCD-grouped work id
    const int ks  = wk >> 8;                       // K-half 0/1
    const int rem = wk & 255;
    const int bm  = rem >> 3, bn = rem & 7;
    const int wm = wave >> 1, wn = wave & 1;
    const int k0 = ks * KHALF;

    // ---- staging setup: 1024 chunks per side, 4 per thread (j=0..3) ----
    const int rowq = wave * 8 + (lane >> 3);
    const int sc   = (lane & 7) ^ (lane >> 3);  // swizzled global chunk
    const unsigned short* gA[4];
    const unsigned short* gB[4];
    #pragma unroll
    for (int j = 0; j < 4; ++j) {
        gA[j] = A + (size_t)(bm * BM + j * 32 + rowq) * K + k0 + sc * 8;
        gB[j] = W + (size_t)(bn * BN + j * 32 + rowq) * K + k0 + sc * 8;
    }
    const int ldsOff = (wave * 64) * 8;     // wave-uniform dest offset (elems)

    // ---- fragment read setup (swizzled) ----
    const int r16 = lane & 15;
    const int p0  = (lane >> 4) ^ (r16 & 7);   // slot for k-half 0 of BK
    const int p1  = p0 ^ 4;                    // slot for k-half 1 of BK
    const int aRowOff = (wm * 64 + r16) * BK;
    const int bRowOff = (wn * 64 + r16) * BK;

    f32x4 acc[4][4];
    #pragma unroll
    for (int m = 0; m < 4; ++m)
        #pragma unroll
        for (int n = 0; n < 4; ++n) acc[m][n] = {0.f, 0.f, 0.f, 0.f};

#define STAGE(SEL, T) do {                                                  \
    _Pragma("unroll")                                                       \
    for (int j = 0; j < 4; ++j)                                             \
        gl_lds16(gA[j] + (size_t)(T) * BK, &lA[SEL][j * 2048 + ldsOff]);    \
    _Pragma("unroll")                                                       \
    for (int j = 0; j < 4; ++j)                                             \
        gl_lds16(gB[j] + (size_t)(T) * BK, &lB[SEL][j * 2048 + ldsOff]);    \
} while (0)

#define COMPUTE(SEL) do {                                                   \
    bf16x8 fa[4][2], fb[4][2];                                              \
    _Pragma("unroll")                                                       \
    for (int m = 0; m < 4; ++m) {                                           \
        fa[m][0] = *(const bf16x8*)(&lA[SEL][aRowOff + m * 16 * BK + p0 * 8]); \
        fa[m][1] = *(const bf16x8*)(&lA[SEL][aRowOff + m * 16 * BK + p1 * 8]); \
    }                                                                       \
    _Pragma("unroll")                                                       \
    for (int n = 0; n < 4; ++n) {                                           \
        fb[n][0] = *(const bf16x8*)(&lB[SEL][bRowOff + n * 16 * BK + p0 * 8]); \
        fb[n][1] = *(const bf16x8*)(&lB[SEL][bRowOff + n * 16 * BK + p1 * 8]); \
    }                                                                       \
    _Pragma("unroll")                                                       \
    for (int h = 0; h < 2; ++h)                                             \
        _Pragma("unroll")                                                   \
        for (int m = 0; m < 4; ++m)                                         \
            _Pragma("unroll")                                               \
            for (int n = 0; n < 4; ++n)                                     \
                acc[m][n] = __builtin_amdgcn_mfma_f32_16x16x32_bf16(        \
                    fa[m][h], fb[n][h], acc[m][n], 0, 0, 0);                \
} while (0)

// drain own staged loads, then workgroup barrier; "memory" clobber pins
// surrounding LDS reads/writes on the correct side.
#define SYNCPIPE() asm volatile("s_waitcnt vmcnt(0)\n\ts_barrier" ::: "memory")

    // prologue: tile 0 into buf0
    STAGE(0, 0);
    SYNCPIPE();
    // steady state: 17 pairs + peeled tail (NT = 36)
    #pragma unroll 1
    for (int it = 0; it < 17; ++it) {
        const int t = 2 * it;
        STAGE(1, t + 1); COMPUTE(0); SYNCPIPE();
        STAGE(0, t + 2); COMPUTE(1); SYNCPIPE();
    }
    STAGE(1, 35); COMPUTE(0); SYNCPIPE();
    COMPUTE(1);

#undef STAGE
#undef COMPUTE
#undef SYNCPIPE

    // epilogue: C/D layout col=lane&15, row=(lane>>4)*4+reg; raw partials
    float* Pk = P + (size_t)ks * B_N * H1DIM;
    const int colbase = bn * BN + wn * 64 + r16;
    const int rowbase = bm * BM + wm * 64 + (lane >> 4) * 4;
    #pragma unroll
    for (int n = 0; n < 4; ++n) {
        const int col = colbase + n * 16;
        #pragma unroll
        for (int m = 0; m < 4; ++m) {
            const int row = rowbase + m * 16;
            #pragma unroll
            for (int j = 0; j < 4; ++j)
                Pk[(size_t)(row + j) * H1DIM + col] = acc[m][n][j];
        }
    }
}

// ---------------------------------------------------------------------------
// GEMM2 (+ fused split-K reduce, bias, relu):
// h[b][:] = relu(P0[b]+P1[b]+b1); out[b][c] = <h, W2[c]> + b2[c].
// One wave per batch row; W2 (16 KB) + b1 (4 KB) staged in LDS.
// ---------------------------------------------------------------------------
__global__ __launch_bounds__(256) void k_gemm2(
    const float* __restrict__ P, const float* __restrict__ W2,
    const float* __restrict__ b1, const float* __restrict__ b2,
    float* __restrict__ out)
{
    __shared__ float w2s[NCLS * H1DIM + H1DIM];
    const int tid = threadIdx.x, lane = tid & 63, wave = tid >> 6;
    const int row = blockIdx.x * 4 + wave;
    for (int i = tid; i < NCLS * H1DIM; i += 256) w2s[i] = W2[i];
    for (int i = tid; i < H1DIM; i += 256) w2s[NCLS * H1DIM + i] = b1[i];
    __syncthreads();

    const float4* p0 = (const float4*)(P + (size_t)row * H1DIM);
    const float4* p1 = (const float4*)(P + (size_t)(B_N + row) * H1DIM);
    const float4* w0 = (const float4*)&w2s[0];
    const float4* w1 = (const float4*)&w2s[H1DIM];
    const float4* w2 = (const float4*)&w2s[2 * H1DIM];
    const float4* w3 = (const float4*)&w2s[3 * H1DIM];
    const float4* bb = (const float4*)&w2s[4 * H1DIM];
    float a0 = 0.f, a1 = 0.f, a2 = 0.f, a3 = 0.f;
    #pragma unroll
    for (int j = 0; j < 4; ++j) {
        const int idx = j * 64 + lane;
        float4 x0 = p0[idx], x1 = p1[idx], bv = bb[idx];
        float4 h;
        h.x = x0.x + x1.x + bv.x; h.x = h.x > 0.f ? h.x : 0.f;
        h.y = x0.y + x1.y + bv.y; h.y = h.y > 0.f ? h.y : 0.f;
        h.z = x0.z + x1.z + bv.z; h.z = h.z > 0.f ? h.z : 0.f;
        h.w = x0.w + x1.w + bv.w; h.w = h.w > 0.f ? h.w : 0.f;
        float4 xv;
        xv = w0[idx]; a0 += h.x*xv.x + h.y*xv.y + h.z*xv.z + h.w*xv.w;
        xv = w1[idx]; a1 += h.x*xv.x + h.y*xv.y + h.z*xv.z + h.w*xv.w;
        xv = w2[idx]; a2 += h.x*xv.x + h.y*xv.y + h.z*xv.z + h.w*xv.w;
        xv = w3[idx]; a3 += h.x*xv.x + h.y*xv.y + h.z*xv.z + h.w*xv.w;
    }
    #pragma unroll
    for (int off = 32; off; off >>= 1) {
        a0 += __shfl_xor(a0, off);
        a1 += __shfl_xor(a1, off);
        a2 += __shfl_xor(a2, off);
        a3 += __shfl_xor(a3, off);
    }
    if (lane == 0) {
        float* o = out + (size_t)row * NCLS;
        o[0] = a0 + b2[0]; o[1] = a1 + b2[1]; o[2] = a2 + b2[2]; o[3] = a3 + b2[3];
    }
}

// ---------------------------------------------------------------------------
// Workspace layout (bytes; ws_size ~3.2 GB per poison-fill counters):
//   [0, 37748736)                 xx bf16          4096*4608*2
//   [37748736, 47185920)          W1 bf16          1024*4608*2
//   [47185920, 80740352)          P f32 partials   2*4096*1024*4
// ---------------------------------------------------------------------------
extern "C" void kernel_launch(void* const* d_in, const int* in_sizes, int n_in,
                              void* d_out, int out_size, void* d_ws, size_t ws_size,
                              hipStream_t stream)
{
    const float* sim_stance = (const float*)d_in[0];
    const float* nli_stance = (const float*)d_in[1];
    const float* sim_body   = (const float*)d_in[2];
    const float* nli_body   = (const float*)d_in[3];
    const float* W1 = (const float*)d_in[4];
    const float* b1 = (const float*)d_in[5];
    const float* W2 = (const float*)d_in[6];
    const float* b2 = (const float*)d_in[7];
    float* out = (float*)d_out;

    char* ws = (char*)d_ws;
    unsigned short* xx  = (unsigned short*)ws;
    unsigned short* w1b = (unsigned short*)(ws + 37748736u);
    float*          P   = (float*)(ws + 37748736u + 9437184u);

    k_f32_to_bf16x4<<<dim3(4608), dim3(256), 0, stream>>>(W1, w1b, 1179648);
    k_topk_gather<<<dim3(B_N), dim3(256), 0, stream>>>(sim_stance, sim_body,
                                                       nli_stance, nli_body, xx);
    k_gemm1<<<dim3(512), dim3(256), 0, stream>>>(xx, w1b, P);
    k_gemm2<<<dim3(1024), dim3(256), 0, stream>>>(P, W2, b1, b2, out);
}